// Round 1
// baseline (211.485 us; speedup 1.0000x reference)
//
#include <hip/hip_runtime.h>

// 2D CDF 5/3 lifting wavelet, fused, register-horizontal + LDS-vertical version.
// Input  x : (24, 1024, 1024) fp32. Output: (8, 12, 512, 512) fp32,
// planes ordered LL(0..2) LH(3..5) HL(6..8) HH(9..11).
//
// v3: LDS cut 30.7KB -> 20.4KB so 8 blocks/CU fit (was 5):
//   - sLH/sHH are aliased into the ODD rows of sS/sD (row 2j+3). Phase B1
//     reads SO/DO[2j+3] and writes LH/HH[2j+3] at the SAME address from the
//     SAME thread (bijective), and Phase B2 only reads even sS/sD rows plus
//     the aliased odd rows -- no cross-thread hazard, no extra barrier.
//   - 71 halo rows (full-res 2r0-4 .. 2r0+66) instead of 72; row 71 was unused.
// Per block: 32x32 half-res tile, 256 threads.
// Phase A: each item loads a 24-float row window from global (float4),
//          computes horizontal d,s in registers, writes 8 s + 8 d via b128.
// Phase B1: LH/HH rows (34x32 each) computed once, written over SO/DO rows.
// Phase B2: one vector item/thread: 8 b128 reads -> 4 float4 global stores.

static __device__ __forceinline__ int mref(int k) {
    // _rpad reflect in half-res index space (N=512): e[-1]->E[1], e[512]->E[510]
    return k < 0 ? 1 : (k > 511 ? 510 : k);
}

__global__ __launch_bounds__(256, 8) void ilwt53_v3(const float* __restrict__ x,
                                                    float* __restrict__ out) {
    const int tid = threadIdx.x;
    const int c0  = blockIdx.x * 32;   // half-res col origin
    const int r0  = blockIdx.y * 32;   // half-res row origin
    const int img = blockIdx.z;        // b*3 + ch
    const int rb  = 2 * r0 - 4;        // full-res row base (4-row halo)

    // row stride 36 floats: keeps b128 alignment (mult of 4) and offsets bank phases
    __shared__ float sS[71 * 36];      // horizontal smooth; odd rows become LH after B1
    __shared__ float sD[71 * 36];      // horizontal detail; odd rows become HH after B1

    const float* __restrict__ xim = x + (size_t)img * (1024 * 1024);

    // ---- Phase A: global -> registers (horizontal lifting) -> LDS ----
    // 71 rows x 4 col-groups = 284 items; item owns half-res cols c..c+7.
    #pragma unroll
    for (int it = 0; it < 2; ++it) {
        int i = tid + it * 256;
        if (i < 284) {
            int lr = i >> 2, g = i & 3;
            int gy = rb + lr; gy = gy < 0 ? 0 : (gy > 1023 ? 1023 : gy);
            const float* __restrict__ row = xim + (size_t)gy * 1024;
            int c  = c0 + 8 * g;       // first owned half-res col
            int fb = 2 * c - 4;        // 24-float full-res window base (16B aligned)

            float w[24];
            if (fb >= 0 && fb + 23 <= 1023) {
                const float4* p = (const float4*)(row + fb);
                #pragma unroll
                for (int q = 0; q < 6; ++q) {
                    float4 v = p[q];
                    w[4*q] = v.x; w[4*q+1] = v.y; w[4*q+2] = v.z; w[4*q+3] = v.w;
                }
            } else {
                #pragma unroll
                for (int q = 0; q < 24; ++q) {
                    int gx = fb + q; gx = gx < 0 ? 0 : (gx > 1023 ? 1023 : gx);
                    w[q] = row[gx];
                }
            }
            // window layout: E[c-2+u] = w[2u], O[c-2+u] = w[2u+1], u = 0..11
            // d[t] is global d[c-1+t], t = 0..9
            float d[10];
            #pragma unroll
            for (int t = 0; t < 10; ++t)
                d[t] = w[2*t+3] - 0.5f * (w[2*t] + w[2*t+4]);
            // horizontal image-edge fixes: d[0] = O[0]-E[1]; d[511] = O[511]-E[510]
            if (c == 0)   d[1] = w[5]  - w[6];    // global j=0  (t=1)
            if (c == 504) d[8] = w[19] - w[16];   // global j=511 (t=8)

            float s[8];
            #pragma unroll
            for (int i2 = 0; i2 < 8; ++i2)
                s[i2] = w[2*i2+4] + 0.25f * (d[i2] + d[i2+2]);
            // s edge fixes: s[0] uses d[m(-1)]=d[1] twice; s[511] uses d[510] twice
            if (c == 0)   s[0] = w[4]  + 0.5f * d[2];   // d[2] is global d[1]
            if (c == 504) s[7] = w[18] + 0.5f * d[7];   // d[7] is global d[510]

            float4* ps = (float4*)(sS + lr * 36 + 8 * g);
            ps[0] = make_float4(s[0], s[1], s[2], s[3]);
            ps[1] = make_float4(s[4], s[5], s[6], s[7]);
            float4* pd = (float4*)(sD + lr * 36 + 8 * g);
            pd[0] = make_float4(d[1], d[2], d[3], d[4]);   // global d[c..c+3]
            pd[1] = make_float4(d[5], d[6], d[7], d[8]);   // global d[c+4..c+7]
        }
    }
    __syncthreads();

    // ---- Phase B1: LH/HH rows computed and written IN PLACE over SO/DO ----
    // 34 k-rows x 8 col-groups = 272 items; each computes LH and HH for 4 cols.
    // LH[j] lives at sS row (2j+3); HH[j] at sD row (2j+3). Each odd-row word
    // is read (as SO/DO) and then written (as LH/HH) by the SAME thread only.
    #pragma unroll
    for (int it = 0; it < 2; ++it) {
        int i = tid + it * 256;
        if (i < 272) {
            int j = i >> 3, ccg = i & 7;
            int k  = r0 - 1 + j;
            int km = mref(k - 1), kp = mref(k + 1);
            int lo = 2 * j + 3;           // SO(k) local full-res row == LH dest row
            int lm = 2 * (km - r0) + 4;   // SE(km), even row
            int lp = 2 * (kp - r0) + 4;   // SE(kp), even row
            int co = 4 * ccg;
            float4 so  = *(const float4*)(sS + lo * 36 + co);
            float4 sem = *(const float4*)(sS + lm * 36 + co);
            float4 sep = *(const float4*)(sS + lp * 36 + co);
            float4 dv  = *(const float4*)(sD + lo * 36 + co);
            float4 dem = *(const float4*)(sD + lm * 36 + co);
            float4 dep = *(const float4*)(sD + lp * 36 + co);
            float4 lh, hh;
            lh.x = so.x - 0.5f * (sem.x + sep.x);
            lh.y = so.y - 0.5f * (sem.y + sep.y);
            lh.z = so.z - 0.5f * (sem.z + sep.z);
            lh.w = so.w - 0.5f * (sem.w + sep.w);
            hh.x = dv.x - 0.5f * (dem.x + dep.x);
            hh.y = dv.y - 0.5f * (dem.y + dep.y);
            hh.z = dv.z - 0.5f * (dem.z + dep.z);
            hh.w = dv.w - 0.5f * (dem.w + dep.w);
            *(float4*)(sS + lo * 36 + co) = lh;   // overwrite SO with LH
            *(float4*)(sD + lo * 36 + co) = hh;   // overwrite DO with HH
        }
    }
    __syncthreads();

    // ---- Phase B2: LL/HL + gather, 4 float4 stores ----
    {
        int rr = tid >> 3, ccg = tid & 7;
        int r  = r0 + rr;
        int km = mref(r - 1), kp = mref(r + 1);
        int jm = km - (r0 - 1), jc = rr + 1, jp = kp - (r0 - 1);
        int le = 2 * rr + 4;              // SE(r)/DE(r) local full-res row (even)
        int co = 4 * ccg;
        float4 se  = *(const float4*)(sS + le * 36 + co);
        float4 de  = *(const float4*)(sD + le * 36 + co);
        float4 lhm = *(const float4*)(sS + (2 * jm + 3) * 36 + co);
        float4 lhc = *(const float4*)(sS + (2 * jc + 3) * 36 + co);
        float4 lhp = *(const float4*)(sS + (2 * jp + 3) * 36 + co);
        float4 hhm = *(const float4*)(sD + (2 * jm + 3) * 36 + co);
        float4 hhc = *(const float4*)(sD + (2 * jc + 3) * 36 + co);
        float4 hhp = *(const float4*)(sD + (2 * jp + 3) * 36 + co);
        float4 ll, hl;
        ll.x = se.x + 0.25f * (lhm.x + lhp.x);
        ll.y = se.y + 0.25f * (lhm.y + lhp.y);
        ll.z = se.z + 0.25f * (lhm.z + lhp.z);
        ll.w = se.w + 0.25f * (lhm.w + lhp.w);
        hl.x = de.x + 0.25f * (hhm.x + hhp.x);
        hl.y = de.y + 0.25f * (hhm.y + hhp.y);
        hl.z = de.z + 0.25f * (hhm.z + hhp.z);
        hl.w = de.w + 0.25f * (hhm.w + hhp.w);

        const size_t plane = 512 * 512;
        float* __restrict__ ob = out + ((size_t)(img / 3) * 12 + (img % 3)) * plane;
        size_t o = (size_t)r * 512 + c0 + co;
        *(float4*)(ob + o)             = ll;
        *(float4*)(ob + o + 3 * plane) = lhc;
        *(float4*)(ob + o + 6 * plane) = hl;
        *(float4*)(ob + o + 9 * plane) = hhc;
    }
}

extern "C" void kernel_launch(void* const* d_in, const int* in_sizes, int n_in,
                              void* d_out, int out_size, void* d_ws, size_t ws_size,
                              hipStream_t stream) {
    const float* x = (const float*)d_in[0];
    float* out = (float*)d_out;
    dim3 grid(16, 16, 24);   // 16x16 half-res tiles per image, 24 images
    dim3 block(256);
    hipLaunchKernelGGL(ilwt53_v3, grid, block, 0, stream, x, out);
}

// Round 2
// 178.291 us; speedup vs baseline: 1.1862x; 1.1862x over previous
//
#include <hip/hip_runtime.h>

// 2D CDF 5/3 lifting wavelet, fused. Input x: (24,1024,1024) fp32.
// Output: (8,12,512,512) fp32, planes LL(0..2) LH(3..5) HL(6..8) HH(9..11).
//
// v4: single-barrier structure.
//   Phase A: global -> registers (horizontal lifting) -> LDS (sS/sD, 71 halo
//            rows, stride 36). Unchanged math from v2/v3.
//   Phase B: ONE pass. Each thread owns one half-res output row r x 4 cols and
//            recomputes the three vertical-detail rows it needs (LH[r-1],LH[r],
//            LH[r+1], same for HH) directly from sS/sD -- ~3x redundant VALU
//            (VALUBusy is only ~12%, don't care) in exchange for deleting the
//            B1 phase, its LDS write-back, and the second __syncthreads.
//   No min-waves launch_bounds: v3 showed forcing 8 blocks/CU squeezes VGPRs
//   to 32 and serializes the Phase-A float4 loads (60->95us). This kernel is
//   ILP-bound, not occupancy-bound. LDS stays 20.4KB so up to 8 blocks/CU fit
//   if registers allow.

static __device__ __forceinline__ int mref(int k) {
    // _rpad reflect in half-res index space (N=512): e[-1]->E[1], e[512]->E[510]
    return k < 0 ? 1 : (k > 511 ? 510 : k);
}

static __device__ __forceinline__ float4 lift_sub(float4 o, float4 em, float4 ep) {
    // o - 0.5*(em+ep)
    float4 r;
    r.x = o.x - 0.5f * (em.x + ep.x);
    r.y = o.y - 0.5f * (em.y + ep.y);
    r.z = o.z - 0.5f * (em.z + ep.z);
    r.w = o.w - 0.5f * (em.w + ep.w);
    return r;
}

static __device__ __forceinline__ float4 lift_add(float4 e, float4 dm, float4 dp) {
    // e + 0.25*(dm+dp)
    float4 r;
    r.x = e.x + 0.25f * (dm.x + dp.x);
    r.y = e.y + 0.25f * (dm.y + dp.y);
    r.z = e.z + 0.25f * (dm.z + dp.z);
    r.w = e.w + 0.25f * (dm.w + dp.w);
    return r;
}

__global__ __launch_bounds__(256) void ilwt53_v4(const float* __restrict__ x,
                                                 float* __restrict__ out) {
    const int tid = threadIdx.x;
    const int c0  = blockIdx.x * 32;   // half-res col origin
    const int r0  = blockIdx.y * 32;   // half-res row origin
    const int img = blockIdx.z;        // b*3 + ch
    const int rb  = 2 * r0 - 4;        // full-res row base (4-row halo)

    // row stride 36 floats: keeps b128 alignment and offsets bank phases
    __shared__ float sS[71 * 36];      // horizontal smooth  (full-res rows rb..rb+70)
    __shared__ float sD[71 * 36];      // horizontal detail

    const float* __restrict__ xim = x + (size_t)img * (1024 * 1024);

    // ---- Phase A: global -> registers (horizontal lifting) -> LDS ----
    // 71 rows x 4 col-groups = 284 items; item owns half-res cols c..c+7.
    #pragma unroll
    for (int it = 0; it < 2; ++it) {
        int i = tid + it * 256;
        if (i < 284) {
            int lr = i >> 2, g = i & 3;
            int gy = rb + lr; gy = gy < 0 ? 0 : (gy > 1023 ? 1023 : gy);
            const float* __restrict__ row = xim + (size_t)gy * 1024;
            int c  = c0 + 8 * g;       // first owned half-res col
            int fb = 2 * c - 4;        // 24-float full-res window base (16B aligned)

            float w[24];
            if (fb >= 0 && fb + 23 <= 1023) {
                const float4* p = (const float4*)(row + fb);
                #pragma unroll
                for (int q = 0; q < 6; ++q) {
                    float4 v = p[q];
                    w[4*q] = v.x; w[4*q+1] = v.y; w[4*q+2] = v.z; w[4*q+3] = v.w;
                }
            } else {
                #pragma unroll
                for (int q = 0; q < 24; ++q) {
                    int gx = fb + q; gx = gx < 0 ? 0 : (gx > 1023 ? 1023 : gx);
                    w[q] = row[gx];
                }
            }
            // window layout: E[c-2+u] = w[2u], O[c-2+u] = w[2u+1], u = 0..11
            float d[10];
            #pragma unroll
            for (int t = 0; t < 10; ++t)
                d[t] = w[2*t+3] - 0.5f * (w[2*t] + w[2*t+4]);
            // horizontal image-edge fixes (reflection collapses the stencil)
            if (c == 0)   d[1] = w[5]  - w[6];    // global j=0
            if (c == 504) d[8] = w[19] - w[16];   // global j=511

            float s[8];
            #pragma unroll
            for (int i2 = 0; i2 < 8; ++i2)
                s[i2] = w[2*i2+4] + 0.25f * (d[i2] + d[i2+2]);
            if (c == 0)   s[0] = w[4]  + 0.5f * d[2];
            if (c == 504) s[7] = w[18] + 0.5f * d[7];

            float4* ps = (float4*)(sS + lr * 36 + 8 * g);
            ps[0] = make_float4(s[0], s[1], s[2], s[3]);
            ps[1] = make_float4(s[4], s[5], s[6], s[7]);
            float4* pd = (float4*)(sD + lr * 36 + 8 * g);
            pd[0] = make_float4(d[1], d[2], d[3], d[4]);
            pd[1] = make_float4(d[5], d[6], d[7], d[8]);
        }
    }
    __syncthreads();

    // ---- Phase B: vertical lifting, fully per-thread, one pass ----
    // Thread owns output row r = r0 + (tid>>3), cols c0+4*(tid&7) .. +3.
    // LH[k] = SO[k] - 0.5*(SE[m(k-1)] + SE[m(k+1)])
    // LL[r] = SE[r] + 0.25*(LH[m(r-1)] + LH[m(r+1)])   (same shape for H side)
    {
        const int rr = tid >> 3, ccg = tid & 7;
        const int r  = r0 + rr;
        const int co = 4 * ccg;
        const int k1 = mref(r - 1), k2 = mref(r + 1);
        const int ka = mref(k1 - 1), kb = mref(k1 + 1);
        const int kc = mref(k2 - 1), kd = mref(k2 + 1);

        // local LDS row of SE[k] is 2*(k-r0)+4, of SO[k] is 2*(k-r0)+5;
        // all indices above fall in [r0-2, r0+33] -> local rows 0..70.
        #define SE_(k) (*(const float4*)(sS + (2 * ((k) - r0) + 4) * 36 + co))
        #define SO_(k) (*(const float4*)(sS + (2 * ((k) - r0) + 5) * 36 + co))
        #define DE_(k) (*(const float4*)(sD + (2 * ((k) - r0) + 4) * 36 + co))
        #define DO_(k) (*(const float4*)(sD + (2 * ((k) - r0) + 5) * 36 + co))

        const size_t plane = 512 * 512;
        float* __restrict__ ob = out + ((size_t)(img / 3) * 12 + (img % 3)) * plane;
        const size_t o = (size_t)r * 512 + c0 + co;

        // ---- L side: LH rows k1, r, k2 -> LL, LH ----
        {
            float4 se_r  = SE_(r);
            float4 se_k1 = SE_(k1);
            float4 se_k2 = SE_(k2);
            float4 se_a  = SE_(ka);
            float4 se_b  = SE_(kb);
            float4 se_c  = SE_(kc);
            float4 se_d  = SE_(kd);
            float4 so_r  = SO_(r);
            float4 so_k1 = SO_(k1);
            float4 so_k2 = SO_(k2);

            float4 lh_c = lift_sub(so_r,  se_k1, se_k2);   // LH[r]
            float4 lh_m = lift_sub(so_k1, se_a,  se_b);    // LH[m(r-1)]
            float4 lh_p = lift_sub(so_k2, se_c,  se_d);    // LH[m(r+1)]
            float4 ll   = lift_add(se_r, lh_m, lh_p);

            *(float4*)(ob + o)             = ll;           // LL plane
            *(float4*)(ob + o + 3 * plane) = lh_c;         // LH plane
        }
        // ---- H side: HH rows k1, r, k2 -> HL, HH ----
        {
            float4 de_r  = DE_(r);
            float4 de_k1 = DE_(k1);
            float4 de_k2 = DE_(k2);
            float4 de_a  = DE_(ka);
            float4 de_b  = DE_(kb);
            float4 de_c  = DE_(kc);
            float4 de_d  = DE_(kd);
            float4 do_r  = DO_(r);
            float4 do_k1 = DO_(k1);
            float4 do_k2 = DO_(k2);

            float4 hh_c = lift_sub(do_r,  de_k1, de_k2);   // HH[r]
            float4 hh_m = lift_sub(do_k1, de_a,  de_b);    // HH[m(r-1)]
            float4 hh_p = lift_sub(do_k2, de_c,  de_d);    // HH[m(r+1)]
            float4 hl   = lift_add(de_r, hh_m, hh_p);

            *(float4*)(ob + o + 6 * plane) = hl;           // HL plane
            *(float4*)(ob + o + 9 * plane) = hh_c;         // HH plane
        }
        #undef SE_
        #undef SO_
        #undef DE_
        #undef DO_
    }
}

extern "C" void kernel_launch(void* const* d_in, const int* in_sizes, int n_in,
                              void* d_out, int out_size, void* d_ws, size_t ws_size,
                              hipStream_t stream) {
    const float* x = (const float*)d_in[0];
    float* out = (float*)d_out;
    dim3 grid(16, 16, 24);   // 16x16 half-res tiles per image, 24 images
    dim3 block(256);
    hipLaunchKernelGGL(ilwt53_v4, grid, block, 0, stream, x, out);
}